// Round 9
// baseline (165.795 us; speedup 1.0000x reference)
//
#include <hip/hip_runtime.h>
#include <math.h>

#define BB 2
#define TT 2048
#define CC 1024
#define UU 1024
#define HH 16
#define DH 64
#define BT (BB*TT)

typedef __attribute__((ext_vector_type(8))) __bf16 bf16x8;
typedef __attribute__((ext_vector_type(4))) __bf16 bf16x4;
typedef __attribute__((ext_vector_type(4))) float f32x4;

#define GLL16(g, l) __builtin_amdgcn_global_load_lds( \
    (__attribute__((address_space(1))) const void*)(g), \
    (__attribute__((address_space(3))) void*)(l), 16, 0, 0)

// log2(e)/8 : folds the 1/sqrt(dh) scale and the exp->exp2 conversion
#define C2EXP 0.18033688011112042f
#define MBIAS 64.0f

// ---------------- fused prep: rowsum-mask + x cast  |  W cast+transpose ----------------
__global__ __launch_bounds__(256) void prep_kernel(
    const float* __restrict__ x, float* __restrict__ kadd, __bf16* __restrict__ xb,
    const float* __restrict__ Wq, const float* __restrict__ Wk,
    const float* __restrict__ Wv, __bf16* __restrict__ Wt) {
    const int bx = blockIdx.x;
    const int t = threadIdx.x;
    if (bx < BT) {
        int row = bx;
        float4 v = *(const float4*)&x[(size_t)row * CC + t * 4];
        bf16x4 o;
        o[0] = (__bf16)v.x; o[1] = (__bf16)v.y; o[2] = (__bf16)v.z; o[3] = (__bf16)v.w;
        *(bf16x4*)&xb[(size_t)row * CC + t * 4] = o;
        float s = v.x + v.y + v.z + v.w;
#pragma unroll
        for (int off = 32; off; off >>= 1) s += __shfl_down(s, off, 64);
        __shared__ float red[4];
        int lane = t & 63, w = t >> 6;
        if (lane == 0) red[w] = s;
        __syncthreads();
        if (t == 0) {
            float tot = red[0] + red[1] + red[2] + red[3];
            kadd[row] = (tot == 0.f ? -1.0e30f : 0.f) - MBIAS;
        }
    } else {
        int bz = bx - BT;
        int z = bz >> 8, rem = bz & 255;
        const float* W = z == 0 ? Wq : (z == 1 ? Wk : Wv);
        __bf16* Out = Wt + (size_t)z * CC * UU;
        __shared__ float tile[64][65];
        int n0 = (rem & 15) * 64, k0 = (rem >> 4) * 64;
        int r = t >> 4, c4 = (t & 15) * 4;
#pragma unroll
        for (int i = 0; i < 4; ++i) {
            float4 v = *(const float4*)&W[(size_t)(k0 + r + i * 16) * UU + n0 + c4];
            tile[r + i * 16][c4 + 0] = v.x; tile[r + i * 16][c4 + 1] = v.y;
            tile[r + i * 16][c4 + 2] = v.z; tile[r + i * 16][c4 + 3] = v.w;
        }
        __syncthreads();
#pragma unroll
        for (int i = 0; i < 4; ++i) {
            int nr = r + i * 16;
            bf16x4 o;
            o[0] = (__bf16)tile[c4 + 0][nr]; o[1] = (__bf16)tile[c4 + 1][nr];
            o[2] = (__bf16)tile[c4 + 2][nr]; o[3] = (__bf16)tile[c4 + 3][nr];
            *(bf16x4*)&Out[(size_t)(n0 + nr) * CC + k0 + c4] = o;
        }
    }
}

// ---------------- QKV GEMM, bf16 MFMA, BK=64, XOR-swizzled LDS ----------------
// Grid (m-tiles=32, n-tiles=8, z=3): XCD = mx%8 (xb m-panels L2-resident per XCD).
// Epilogue: cw is wave-private; single barrier protects the As alias.
__global__ __launch_bounds__(256, 4) void qkv_mfma(
    const __bf16* __restrict__ xb, const __bf16* __restrict__ Wt_all,
    const float* __restrict__ bq, const float* __restrict__ bk,
    const float* __restrict__ bv,
    __bf16* __restrict__ Qo, __bf16* __restrict__ Ko, __bf16* __restrict__ VTo) {
    const int z = blockIdx.z;
    const __bf16* Wt = Wt_all + (size_t)z * CC * UU;
    const float* bias = z == 0 ? bq : (z == 1 ? bk : bv);

    const int m0 = blockIdx.x * 128, n0 = blockIdx.y * 128;
    const int t = threadIdx.x, w = t >> 6, lane = t & 63;
    const int quad = lane >> 4, nn = lane & 15;
    const int wr = w >> 1, wc = w & 1;

    __shared__ __bf16 smem[2 * 128 * 64];
    __bf16* As = smem;
    __bf16* Bs = smem + 128 * 64;

    f32x4 acc[4][4];
#pragma unroll
    for (int i = 0; i < 4; ++i)
#pragma unroll
        for (int j = 0; j < 4; ++j) acc[i][j] = (f32x4){0.f, 0.f, 0.f, 0.f};

    for (int k0 = 0; k0 < CC; k0 += 64) {
        __syncthreads();
#pragma unroll
        for (int i = 0; i < 4; ++i) {
            int c = i * 256 + t;
            int row = c >> 3;
            int gc = ((c & 7) ^ (row & 7)) * 8;
            GLL16(&xb[(size_t)(m0 + row) * CC + k0 + gc], &As[c * 8]);
            GLL16(&Wt[(size_t)(n0 + row) * CC + k0 + gc], &Bs[c * 8]);
        }
        __syncthreads();
#pragma unroll
        for (int kk = 0; kk < 2; ++kk) {
            bf16x8 af[4], bfr[4];
#pragma unroll
            for (int i = 0; i < 4; ++i) {
                int R = wr * 64 + i * 16 + nn;
                af[i] = *(const bf16x8*)&As[R * 64 + (((kk * 4 + quad) ^ (R & 7)) * 8)];
            }
#pragma unroll
            for (int j = 0; j < 4; ++j) {
                int R = wc * 64 + j * 16 + nn;
                bfr[j] = *(const bf16x8*)&Bs[R * 64 + (((kk * 4 + quad) ^ (R & 7)) * 8)];
            }
#pragma unroll
            for (int i = 0; i < 4; ++i)
#pragma unroll
                for (int j = 0; j < 4; ++j)
                    acc[i][j] = __builtin_amdgcn_mfma_f32_16x16x32_bf16(af[i], bfr[j], acc[i][j], 0, 0, 0);
        }
    }

    __bf16* cw = &smem[w * 1024];
    float bv4[4];
#pragma unroll
    for (int j = 0; j < 4; ++j) bv4[j] = bias[n0 + wc * 64 + j * 16 + nn];

    // single barrier: all waves done reading As/Bs before cw (aliases As) is written
    __syncthreads();

    if (z < 2) {
        __bf16* Out = z == 0 ? Qo : Ko;
#pragma unroll
        for (int i = 0; i < 4; ++i) {
#pragma unroll
            for (int j = 0; j < 4; ++j)
#pragma unroll
                for (int r = 0; r < 4; ++r)
                    cw[(quad * 4 + r) * 64 + j * 16 + nn] =
                        (__bf16)fmaxf(acc[i][j][r] + bv4[j], 0.f);
            int rr = lane >> 2, cc = (lane & 3) * 16;
            bf16x8 v0 = *(const bf16x8*)&cw[rr * 64 + cc];
            bf16x8 v1 = *(const bf16x8*)&cw[rr * 64 + cc + 8];
            size_t o = (size_t)(m0 + wr * 64 + i * 16 + rr) * UU + n0 + wc * 64 + cc;
            *(bf16x8*)&Out[o] = v0;
            *(bf16x8*)&Out[o + 8] = v1;
        }
    } else {
#pragma unroll
        for (int i = 0; i < 4; ++i) {
#pragma unroll
            for (int j = 0; j < 4; ++j)
#pragma unroll
                for (int r = 0; r < 4; ++r)
                    cw[(j * 16 + nn) * 16 + quad * 4 + r] =
                        (__bf16)fmaxf(acc[i][j][r] + bv4[j], 0.f);
            bf16x8 v0 = *(const bf16x8*)&cw[lane * 16];
            bf16x8 v1 = *(const bf16x8*)&cw[lane * 16 + 8];
            size_t o = (size_t)(n0 + wc * 64 + lane) * BT + m0 + wr * 64 + i * 16;
            *(bf16x8*)&VTo[o] = v0;
            *(bf16x8*)&VTo[o + 8] = v1;
        }
    }
}

// ---------------- MFMA flash attention: fused dual-job key stream ----------------
// Round-5 16x16 core (proven fastest) + NEW: half-0 blocks merge job A (q-tile p,
// keys 0..p) and job B1 (q-tile 31-p, keys 0..15-p) over ONE shared key stream:
// iterations drop 17+16 -> max(p+1,16-p) (per-CU slot sum 50 vs 68, constant),
// dual-active iterations carry two INDEPENDENT QK->softmax->PV chains (PV_A
// overlaps QK_B - the ILP the serial version lacked), and each staged K/V tile
// serves both jobs. ps is shared sequentially (A writes/reads, then B): rows are
// wave-private and same-wave DS ops are in-order -> no extra barrier, LDS stays
// 40 KiB -> 4 blocks/CU. Half-1 (job B2, 16 iters, diag last) unchanged.
__global__ __launch_bounds__(256, 4) void attn_mfma(
    const __bf16* __restrict__ Q, const __bf16* __restrict__ K,
    const __bf16* __restrict__ Vt, const float* __restrict__ kadd,
    __bf16* __restrict__ Obf, float* __restrict__ Op0, float* __restrict__ Op1,
    float* __restrict__ lq0, float* __restrict__ lq1) {
    const int bh = blockIdx.x, b = bh >> 4, h = bh & 15;   // XCD = bh%8
    const int cx = blockIdx.y;                              // 0..31 pair/half
    const int p = cx >> 1, half = cx & 1;
    const int col0 = h * 64, rowbase = b * TT;
    const int qa = p, qb = 31 - p;

    const int t = threadIdx.x;
    const int w = t >> 6, lane = t & 63, quad = lane >> 4, nn = lane & 15;
    const int s7 = nn & 7;

    __shared__ __align__(16) __bf16 ks[2][64 * 64];
    __shared__ __align__(16) __bf16 vt[2][64 * 64];
    __shared__ __align__(16) __bf16 ps[64 * 64];   // P (wave-private rows, time-shared A/B)

    const int c0 = t;
    const int r0 = c0 >> 3, g0 = ((c0 & 7) ^ (r0 & 7)) * 8;
    const int prow = 16 * w + nn;

    const size_t KSTRIDE = 64 * (size_t)UU;
    const __bf16* kb0 = &K[(size_t)(rowbase + r0) * UU + col0 + g0];
    const __bf16* kb1 = kb0 + 32 * (size_t)UU;
    const __bf16* vb0 = &Vt[(size_t)(col0 + r0) * BT + rowbase + g0];
    const __bf16* vb1 = vb0 + 32 * (size_t)BT;
    const float* kab = &kadd[rowbase + quad * 4];

#define STAGE_TILE(BUF, KP0, KP1, VP0, VP1)   \
    GLL16((KP0), &ks[BUF][c0 * 8]);           \
    GLL16((KP1), &ks[BUF][c0 * 8 + 2048]);    \
    GLL16((VP0), &vt[BUF][c0 * 8]);           \
    GLL16((VP1), &vt[BUF][c0 * 8 + 2048]);

#define LOADKA(KT)                            \
    _Pragma("unroll")                         \
    for (int ct = 0; ct < 4; ++ct)            \
        ka[ct] = *(const f32x4*)&kab[(KT) * 64 + ct * 16];

    float lpA = 0.f, lpB = 0.f;
    f32x4 ocA[4], ocB[4];
#pragma unroll
    for (int dt = 0; dt < 4; ++dt) {
        ocA[dt] = (f32x4){0.f, 0.f, 0.f, 0.f};
        ocB[dt] = (f32x4){0.f, 0.f, 0.f, 0.f};
    }
    int cur = 0;
    f32x4 ka[4];
    bf16x8 bqA0, bqA1, bqB0, bqB1;

// one 64q x 64k core: QK (swapped operands) + softmax + P via wave-private ps + PV
#define ATTN_CORE(KSC, VTC, DIAG, BQ0, BQ1, LP, OC)                            \
  {                                                                            \
    const __bf16* ksc = (KSC);                                                 \
    const __bf16* vtc = (VTC);                                                 \
    _Pragma("unroll")                                                          \
    for (int ct = 0; ct < 4; ++ct) {                                           \
      int krow = ct * 16 + nn;                                                 \
      bf16x8 a0 = *(const bf16x8*)&ksc[krow * 64 + ((quad ^ s7) * 8)];         \
      bf16x8 a1 = *(const bf16x8*)&ksc[krow * 64 + (((4 + quad) ^ s7) * 8)];   \
      f32x4 sc = (f32x4){0.f, 0.f, 0.f, 0.f};                                  \
      __builtin_amdgcn_s_setprio(1);                                           \
      sc = __builtin_amdgcn_mfma_f32_16x16x32_bf16(a0, (BQ0), sc, 0, 0, 0);    \
      sc = __builtin_amdgcn_mfma_f32_16x16x32_bf16(a1, (BQ1), sc, 0, 0, 0);    \
      __builtin_amdgcn_s_setprio(0);                                           \
      bf16x4 pw;                                                               \
      _Pragma("unroll")                                                        \
      for (int r = 0; r < 4; ++r) {                                            \
        float arg = fmaf(sc[r], C2EXP, ka[ct][r]);                             \
        if (DIAG) {                                                            \
          int kl = ct * 16 + quad * 4 + r;                                     \
          if (kl > prow) arg = -1.0e30f;                                       \
        }                                                                      \
        float pv = __builtin_amdgcn_exp2f(arg);                                \
        (LP) += pv;                                                            \
        pw[r] = (__bf16)pv;                                                    \
      }                                                                        \
      int chunk = ct * 2 + (quad >> 1);                                        \
      *(bf16x4*)&ps[prow * 64 + ((chunk ^ s7) * 8) + (quad & 1) * 4] = pw;     \
    }                                                                          \
    bf16x8 bp0 = *(const bf16x8*)&ps[prow * 64 + ((quad ^ s7) * 8)];           \
    bf16x8 bp1 = *(const bf16x8*)&ps[prow * 64 + (((4 + quad) ^ s7) * 8)];     \
    __builtin_amdgcn_s_setprio(1);                                             \
    _Pragma("unroll")                                                          \
    for (int dt = 0; dt < 4; ++dt) {                                           \
      int vrow = dt * 16 + nn;                                                 \
      bf16x8 a0 = *(const bf16x8*)&vtc[vrow * 64 + ((quad ^ s7) * 8)];         \
      bf16x8 a1 = *(const bf16x8*)&vtc[vrow * 64 + (((4 + quad) ^ s7) * 8)];   \
      (OC)[dt] = __builtin_amdgcn_mfma_f32_16x16x32_bf16(a0, bp0, (OC)[dt], 0, 0, 0); \
      (OC)[dt] = __builtin_amdgcn_mfma_f32_16x16x32_bf16(a1, bp1, (OC)[dt], 0, 0, 0); \
    }                                                                          \
    __builtin_amdgcn_s_setprio(0);                                             \
  }

    if (half == 0) {
        // ---------- fused jobs: A = q-tile qa keys 0..qa (diag at kt==qa),
        //                        B1 = q-tile qb keys 0..15-p (never diag) ----------
        const int nA = qa + 1, nB = 16 - p;
        const int nmax = nA > nB ? nA : nB;
        {
            const __bf16* qrp = &Q[(size_t)(rowbase + qa * 64 + prow) * UU + col0];
            bqA0 = *(const bf16x8*)&qrp[quad * 8];
            bqA1 = *(const bf16x8*)&qrp[32 + quad * 8];
            const __bf16* qrq = &Q[(size_t)(rowbase + qb * 64 + prow) * UU + col0];
            bqB0 = *(const bf16x8*)&qrq[quad * 8];
            bqB1 = *(const bf16x8*)&qrq[32 + quad * 8];
        }
        const __bf16* kp0 = kb0; const __bf16* kp1 = kb1;
        const __bf16* vp0 = vb0; const __bf16* vp1 = vb1;
        STAGE_TILE(0, kp0, kp1, vp0, vp1)
        kp0 += KSTRIDE; kp1 += KSTRIDE; vp0 += 64; vp1 += 64;
        asm volatile("s_waitcnt vmcnt(0)" ::: "memory");
        __builtin_amdgcn_s_barrier();

        for (int kt = 0; kt < nmax; ++kt) {
            LOADKA(kt)
            __builtin_amdgcn_sched_barrier(0);
            if (kt + 1 < nmax) {
                STAGE_TILE(cur ^ 1, kp0, kp1, vp0, vp1)
                kp0 += KSTRIDE; kp1 += KSTRIDE; vp0 += 64; vp1 += 64;
            }
            __builtin_amdgcn_sched_barrier(0);
            if (kt < nA) {
                ATTN_CORE(ks[cur], vt[cur], kt == qa, bqA0, bqA1, lpA, ocA)
            }
            if (kt < nB) {
                ATTN_CORE(ks[cur], vt[cur], false, bqB0, bqB1, lpB, ocB)
            }
            cur ^= 1;
            if (kt + 1 < nmax) {
                asm volatile("s_waitcnt vmcnt(0)" ::: "memory");
                __builtin_amdgcn_s_barrier();
            }
        }
        // epilogue A: COMPLETE output for q-tile qa -> final bf16 (qsel & /l applied)
        {
            float l = lpA;
            l += __shfl_xor(l, 16, 64);
            l += __shfl_xor(l, 32, 64);
            const int grow = rowbase + qa * 64 + prow;
            float qsel = (kadd[grow] < -1.0e29f) ? 0.f : 1.f;
            float mult = qsel / fmaxf(l, 1e-37f);
#pragma unroll
            for (int dt = 0; dt < 4; ++dt) {
                bf16x4 ov;
                ov[0] = (__bf16)(ocA[dt][0] * mult); ov[1] = (__bf16)(ocA[dt][1] * mult);
                ov[2] = (__bf16)(ocA[dt][2] * mult); ov[3] = (__bf16)(ocA[dt][3] * mult);
                *(bf16x4*)&Obf[(size_t)grow * UU + col0 + dt * 16 + quad * 4] = ov;
            }
        }
        // epilogue B1: f32 partial (compact upper-half rows) + l
        {
            float l = lpB;
            l += __shfl_xor(l, 16, 64);
            l += __shfl_xor(l, 32, 64);
            const int grow = rowbase + qb * 64 + prow;
            if (quad == 0) lq0[(size_t)grow * HH + h] = l;
            size_t orow = (size_t)(grow - (b + 1) * 1024);
#pragma unroll
            for (int dt = 0; dt < 4; ++dt)
                *(f32x4*)&Op0[orow * UU + col0 + dt * 16 + quad * 4] = ocB[dt];
        }
    } else {
        // ---------- job B part 2: q-tile qb, key tiles 16-p..31-p (diag last) ----------
        const int k0t = 16 - p;
        {
            const __bf16* qrow = &Q[(size_t)(rowbase + qb * 64 + prow) * UU + col0];
            bqA0 = *(const bf16x8*)&qrow[quad * 8];
            bqA1 = *(const bf16x8*)&qrow[32 + quad * 8];
        }
        const __bf16* kp0 = kb0 + (size_t)k0t * KSTRIDE;
        const __bf16* kp1 = kb1 + (size_t)k0t * KSTRIDE;
        const __bf16* vp0 = vb0 + k0t * 64;
        const __bf16* vp1 = vb1 + k0t * 64;
        STAGE_TILE(0, kp0, kp1, vp0, vp1)
        kp0 += KSTRIDE; kp1 += KSTRIDE; vp0 += 64; vp1 += 64;
        asm volatile("s_waitcnt vmcnt(0)" ::: "memory");
        __builtin_amdgcn_s_barrier();

        for (int i = 0; i < 15; ++i) {
            LOADKA(k0t + i)
            __builtin_amdgcn_sched_barrier(0);
            STAGE_TILE(cur ^ 1, kp0, kp1, vp0, vp1)
            kp0 += KSTRIDE; kp1 += KSTRIDE; vp0 += 64; vp1 += 64;
            __builtin_amdgcn_sched_barrier(0);
            ATTN_CORE(ks[cur], vt[cur], false, bqA0, bqA1, lpA, ocA)
            cur ^= 1;
            asm volatile("s_waitcnt vmcnt(0)" ::: "memory");
            __builtin_amdgcn_s_barrier();
        }
        LOADKA(k0t + 15)
        ATTN_CORE(ks[cur], vt[cur], true, bqA0, bqA1, lpA, ocA)  // kt = qb: diagonal
        // epilogue B2: f32 partial (compact upper-half rows) + l
        {
            float l = lpA;
            l += __shfl_xor(l, 16, 64);
            l += __shfl_xor(l, 32, 64);
            const int grow = rowbase + qb * 64 + prow;
            if (quad == 0) lq1[(size_t)grow * HH + h] = l;
            size_t orow = (size_t)(grow - (b + 1) * 1024);
#pragma unroll
            for (int dt = 0; dt < 4; ++dt)
                *(f32x4*)&Op1[orow * UU + col0 + dt * 16 + quad * 4] = ocA[dt];
        }
    }
#undef ATTN_CORE
#undef STAGE_TILE
#undef LOADKA
}

// ---------------- combine partials + residual + layernorm ----------------
__global__ __launch_bounds__(256) void ln_kernel(
    const __bf16* __restrict__ Obf, const float* __restrict__ Op0,
    const float* __restrict__ Op1, const float* __restrict__ lq0,
    const float* __restrict__ lq1, const float* __restrict__ kadd,
    const float* __restrict__ x, const float* __restrict__ gamma,
    const float* __restrict__ beta, float* __restrict__ out) {
    int row = blockIdx.x;
    int b = row >> 11;
    int qt = (row & (TT - 1)) >> 6;
    size_t base = (size_t)row * UU;
    int t = threadIdx.x;
    float v0, v1, v2, v3;
    float4 xv = *(const float4*)&x[base + t * 4];
    if (qt < 16) {
        // lower half: attention output is final bf16 (mask & /l already applied)
        bf16x4 ov = *(const bf16x4*)&Obf[base + t * 4];
        v0 = (float)ov[0] + xv.x; v1 = (float)ov[1] + xv.y;
        v2 = (float)ov[2] + xv.z; v3 = (float)ov[3] + xv.w;
    } else {
        // upper half: combine the two f32 partials
        int h = t >> 4;
        float l = lq0[(size_t)row * HH + h] + lq1[(size_t)row * HH + h];
        size_t base1 = (size_t)(row - (b + 1) * 1024) * UU;
        f32x4 o0 = *(const f32x4*)&Op0[base1 + t * 4];
        f32x4 o1 = *(const f32x4*)&Op1[base1 + t * 4];
        float qsel = (kadd[row] < -1.0e29f) ? 0.f : 1.f;
        float mult = qsel / fmaxf(l, 1e-37f);
        v0 = (o0[0] + o1[0]) * mult + xv.x; v1 = (o0[1] + o1[1]) * mult + xv.y;
        v2 = (o0[2] + o1[2]) * mult + xv.z; v3 = (o0[3] + o1[3]) * mult + xv.w;
    }
    float s1 = v0 + v1 + v2 + v3;
    float s2 = v0 * v0 + v1 * v1 + v2 * v2 + v3 * v3;
#pragma unroll
    for (int off = 32; off; off >>= 1) {
        s1 += __shfl_down(s1, off, 64);
        s2 += __shfl_down(s2, off, 64);
    }
    __shared__ float r1[4], r2[4];
    int lane = t & 63, w = t >> 6;
    if (lane == 0) { r1[w] = s1; r2[w] = s2; }
    __syncthreads();
    s1 = r1[0] + r1[1] + r1[2] + r1[3];
    s2 = r2[0] + r2[1] + r2[2] + r2[3];
    float mean = s1 * (1.0f / 1024.0f);
    float var = s2 * (1.0f / 1024.0f) - mean * mean;
    float rstd = rsqrtf(var + 1e-8f);
    float4 g = *(const float4*)&gamma[t * 4];
    float4 be = *(const float4*)&beta[t * 4];
    float4 ores;
    ores.x = g.x * (v0 - mean) * rstd + be.x;
    ores.y = g.y * (v1 - mean) * rstd + be.y;
    ores.z = g.z * (v2 - mean) * rstd + be.z;
    ores.w = g.w * (v3 - mean) * rstd + be.w;
    *(float4*)&out[base + t * 4] = ores;
}

extern "C" void kernel_launch(void* const* d_in, const int* in_sizes, int n_in,
                              void* d_out, int out_size, void* d_ws, size_t ws_size,
                              hipStream_t stream) {
    const float* x     = (const float*)d_in[0];
    const float* Wq    = (const float*)d_in[1];
    const float* bq    = (const float*)d_in[2];
    const float* Wk    = (const float*)d_in[3];
    const float* bk    = (const float*)d_in[4];
    const float* Wv    = (const float*)d_in[5];
    const float* bv    = (const float*)d_in[6];
    const float* gamma = (const float*)d_in[7];
    const float* beta  = (const float*)d_in[8];
    float* out = (float*)d_out;

    char* wsb = (char*)d_ws;
    const size_t MB = 1024ull * 1024;
    __bf16* xb  = (__bf16*)(wsb);                // 0..8 MiB   (dead after qkv)
    __bf16* Wt  = (__bf16*)(wsb + 8 * MB);       // 8..14 MiB  (dead after qkv)
    __bf16* Obf = (__bf16*)(wsb);                // 0..8 MiB   (aliases xb; lower-half rows)
    float* Op0  = (float*)(wsb + 8 * MB);        // 8..16 MiB  (aliases Wt; compact upper rows)
    __bf16* Qb  = (__bf16*)(wsb + 16 * MB);      // 8 MiB
    __bf16* Kb  = (__bf16*)(wsb + 24 * MB);      // 8 MiB
    __bf16* Vt  = (__bf16*)(wsb + 32 * MB);      // 8 MiB
    float* kadd = (float*)(wsb + 40 * MB);       // 16 KiB
    float* Op1  = (float*)(wsb + 41 * MB);       // 8 MiB (compact upper rows)
    float* lq0  = (float*)(wsb + 49 * MB);       // 256 KiB
    float* lq1  = (float*)(wsb + 50 * MB);       // 256 KiB

    prep_kernel<<<dim3(BT + 768), dim3(256), 0, stream>>>(x, kadd, xb, Wq, Wk, Wv, Wt);
    qkv_mfma<<<dim3(BT / 128, UU / 128, 3), dim3(256), 0, stream>>>(
        xb, Wt, bq, bk, bv, Qb, Kb, Vt);
    attn_mfma<<<dim3(BB * HH, 32), dim3(256), 0, stream>>>(
        Qb, Kb, Vt, kadd, Obf, Op0, Op1, lq0, lq1);
    ln_kernel<<<dim3(BT), dim3(256), 0, stream>>>(
        Obf, Op0, Op1, lq0, lq1, kadd, x, gamma, beta, out);
}

// Round 10
// 162.815 us; speedup vs baseline: 1.0183x; 1.0183x over previous
//
#include <hip/hip_runtime.h>
#include <math.h>

#define BB 2
#define TT 2048
#define CC 1024
#define UU 1024
#define HH 16
#define DH 64
#define BT (BB*TT)

typedef __attribute__((ext_vector_type(8))) __bf16 bf16x8;
typedef __attribute__((ext_vector_type(4))) __bf16 bf16x4;
typedef __attribute__((ext_vector_type(4))) float f32x4;

#define GLL16(g, l) __builtin_amdgcn_global_load_lds( \
    (__attribute__((address_space(1))) const void*)(g), \
    (__attribute__((address_space(3))) void*)(l), 16, 0, 0)

// log2(e)/8 : folds the 1/sqrt(dh) scale and the exp->exp2 conversion
#define C2EXP 0.18033688011112042f
#define MBIAS 64.0f

// ---------------- fused prep: rowsum-mask + x cast  |  W cast+transpose ----------------
__global__ __launch_bounds__(256) void prep_kernel(
    const float* __restrict__ x, float* __restrict__ kadd, __bf16* __restrict__ xb,
    const float* __restrict__ Wq, const float* __restrict__ Wk,
    const float* __restrict__ Wv, __bf16* __restrict__ Wt) {
    const int bx = blockIdx.x;
    const int t = threadIdx.x;
    if (bx < BT) {
        int row = bx;
        float4 v = *(const float4*)&x[(size_t)row * CC + t * 4];
        bf16x4 o;
        o[0] = (__bf16)v.x; o[1] = (__bf16)v.y; o[2] = (__bf16)v.z; o[3] = (__bf16)v.w;
        *(bf16x4*)&xb[(size_t)row * CC + t * 4] = o;
        float s = v.x + v.y + v.z + v.w;
#pragma unroll
        for (int off = 32; off; off >>= 1) s += __shfl_down(s, off, 64);
        __shared__ float red[4];
        int lane = t & 63, w = t >> 6;
        if (lane == 0) red[w] = s;
        __syncthreads();
        if (t == 0) {
            float tot = red[0] + red[1] + red[2] + red[3];
            kadd[row] = (tot == 0.f ? -1.0e30f : 0.f) - MBIAS;
        }
    } else {
        int bz = bx - BT;
        int z = bz >> 8, rem = bz & 255;
        const float* W = z == 0 ? Wq : (z == 1 ? Wk : Wv);
        __bf16* Out = Wt + (size_t)z * CC * UU;
        __shared__ float tile[64][65];
        int n0 = (rem & 15) * 64, k0 = (rem >> 4) * 64;
        int r = t >> 4, c4 = (t & 15) * 4;
#pragma unroll
        for (int i = 0; i < 4; ++i) {
            float4 v = *(const float4*)&W[(size_t)(k0 + r + i * 16) * UU + n0 + c4];
            tile[r + i * 16][c4 + 0] = v.x; tile[r + i * 16][c4 + 1] = v.y;
            tile[r + i * 16][c4 + 2] = v.z; tile[r + i * 16][c4 + 3] = v.w;
        }
        __syncthreads();
#pragma unroll
        for (int i = 0; i < 4; ++i) {
            int nr = r + i * 16;
            bf16x4 o;
            o[0] = (__bf16)tile[c4 + 0][nr]; o[1] = (__bf16)tile[c4 + 1][nr];
            o[2] = (__bf16)tile[c4 + 2][nr]; o[3] = (__bf16)tile[c4 + 3][nr];
            *(bf16x4*)&Out[(size_t)(n0 + nr) * CC + k0 + c4] = o;
        }
    }
}

// ---------------- QKV GEMM, bf16 MFMA, BK=64, XOR-swizzled LDS ----------------
// Grid (m-tiles=32, n-tiles=8, z=3): XCD = mx%8 (xb m-panels L2-resident per XCD).
// Epilogue: cw is wave-private; single barrier protects the As alias.
__global__ __launch_bounds__(256, 4) void qkv_mfma(
    const __bf16* __restrict__ xb, const __bf16* __restrict__ Wt_all,
    const float* __restrict__ bq, const float* __restrict__ bk,
    const float* __restrict__ bv,
    __bf16* __restrict__ Qo, __bf16* __restrict__ Ko, __bf16* __restrict__ VTo) {
    const int z = blockIdx.z;
    const __bf16* Wt = Wt_all + (size_t)z * CC * UU;
    const float* bias = z == 0 ? bq : (z == 1 ? bk : bv);

    const int m0 = blockIdx.x * 128, n0 = blockIdx.y * 128;
    const int t = threadIdx.x, w = t >> 6, lane = t & 63;
    const int quad = lane >> 4, nn = lane & 15;
    const int wr = w >> 1, wc = w & 1;

    __shared__ __bf16 smem[2 * 128 * 64];
    __bf16* As = smem;
    __bf16* Bs = smem + 128 * 64;

    f32x4 acc[4][4];
#pragma unroll
    for (int i = 0; i < 4; ++i)
#pragma unroll
        for (int j = 0; j < 4; ++j) acc[i][j] = (f32x4){0.f, 0.f, 0.f, 0.f};

    for (int k0 = 0; k0 < CC; k0 += 64) {
        __syncthreads();
#pragma unroll
        for (int i = 0; i < 4; ++i) {
            int c = i * 256 + t;
            int row = c >> 3;
            int gc = ((c & 7) ^ (row & 7)) * 8;
            GLL16(&xb[(size_t)(m0 + row) * CC + k0 + gc], &As[c * 8]);
            GLL16(&Wt[(size_t)(n0 + row) * CC + k0 + gc], &Bs[c * 8]);
        }
        __syncthreads();
#pragma unroll
        for (int kk = 0; kk < 2; ++kk) {
            bf16x8 af[4], bfr[4];
#pragma unroll
            for (int i = 0; i < 4; ++i) {
                int R = wr * 64 + i * 16 + nn;
                af[i] = *(const bf16x8*)&As[R * 64 + (((kk * 4 + quad) ^ (R & 7)) * 8)];
            }
#pragma unroll
            for (int j = 0; j < 4; ++j) {
                int R = wc * 64 + j * 16 + nn;
                bfr[j] = *(const bf16x8*)&Bs[R * 64 + (((kk * 4 + quad) ^ (R & 7)) * 8)];
            }
#pragma unroll
            for (int i = 0; i < 4; ++i)
#pragma unroll
                for (int j = 0; j < 4; ++j)
                    acc[i][j] = __builtin_amdgcn_mfma_f32_16x16x32_bf16(af[i], bfr[j], acc[i][j], 0, 0, 0);
        }
    }

    __bf16* cw = &smem[w * 1024];
    float bv4[4];
#pragma unroll
    for (int j = 0; j < 4; ++j) bv4[j] = bias[n0 + wc * 64 + j * 16 + nn];

    // single barrier: all waves done reading As/Bs before cw (aliases As) is written
    __syncthreads();

    if (z < 2) {
        __bf16* Out = z == 0 ? Qo : Ko;
#pragma unroll
        for (int i = 0; i < 4; ++i) {
#pragma unroll
            for (int j = 0; j < 4; ++j)
#pragma unroll
                for (int r = 0; r < 4; ++r)
                    cw[(quad * 4 + r) * 64 + j * 16 + nn] =
                        (__bf16)fmaxf(acc[i][j][r] + bv4[j], 0.f);
            int rr = lane >> 2, cc = (lane & 3) * 16;
            bf16x8 v0 = *(const bf16x8*)&cw[rr * 64 + cc];
            bf16x8 v1 = *(const bf16x8*)&cw[rr * 64 + cc + 8];
            size_t o = (size_t)(m0 + wr * 64 + i * 16 + rr) * UU + n0 + wc * 64 + cc;
            *(bf16x8*)&Out[o] = v0;
            *(bf16x8*)&Out[o + 8] = v1;
        }
    } else {
#pragma unroll
        for (int i = 0; i < 4; ++i) {
#pragma unroll
            for (int j = 0; j < 4; ++j)
#pragma unroll
                for (int r = 0; r < 4; ++r)
                    cw[(j * 16 + nn) * 16 + quad * 4 + r] =
                        (__bf16)fmaxf(acc[i][j][r] + bv4[j], 0.f);
            bf16x8 v0 = *(const bf16x8*)&cw[lane * 16];
            bf16x8 v1 = *(const bf16x8*)&cw[lane * 16 + 8];
            size_t o = (size_t)(n0 + wc * 64 + lane) * BT + m0 + wr * 64 + i * 16;
            *(bf16x8*)&VTo[o] = v0;
            *(bf16x8*)&VTo[o + 8] = v1;
        }
    }
}

// ---------------- MFMA flash attention: fused dual-job key stream, CU-balanced ----------------
// Round-9 fused core + NEW bijective cx decode: p = (cx&7) | ((cx>>4)<<3),
// half = (cx>>3)&1. Same-CU blocks are {id, id+256, id+512, id+768} -> cx set
// {c, c+8, c+16, c+24} -> this CU hosts (p=c, h0), (p=c, h1), (p=c+8, h0),
// (p=c+8, h1). Half-0 slots nmax(c)+nmax(c+8) = (16-c)+(c+9) = 25 for ALL c,
// half-1 = 16 each -> per-CU slot sum = 57, constant (round 9's p/p+4 pairing
// ranged 53-60). Everything else identical to the proven round-9 kernel.
__global__ __launch_bounds__(256, 4) void attn_mfma(
    const __bf16* __restrict__ Q, const __bf16* __restrict__ K,
    const __bf16* __restrict__ Vt, const float* __restrict__ kadd,
    __bf16* __restrict__ Obf, float* __restrict__ Op0, float* __restrict__ Op1,
    float* __restrict__ lq0, float* __restrict__ lq1) {
    const int bh = blockIdx.x, b = bh >> 4, h = bh & 15;   // XCD = bh%8
    const int cx = blockIdx.y;                              // 0..31
    const int p = (cx & 7) | ((cx >> 4) << 3);              // balanced decode
    const int half = (cx >> 3) & 1;
    const int col0 = h * 64, rowbase = b * TT;
    const int qa = p, qb = 31 - p;

    const int t = threadIdx.x;
    const int w = t >> 6, lane = t & 63, quad = lane >> 4, nn = lane & 15;
    const int s7 = nn & 7;

    __shared__ __align__(16) __bf16 ks[2][64 * 64];
    __shared__ __align__(16) __bf16 vt[2][64 * 64];
    __shared__ __align__(16) __bf16 ps[64 * 64];   // P (wave-private rows, time-shared A/B)

    const int c0 = t;
    const int r0 = c0 >> 3, g0 = ((c0 & 7) ^ (r0 & 7)) * 8;
    const int prow = 16 * w + nn;

    const size_t KSTRIDE = 64 * (size_t)UU;
    const __bf16* kb0 = &K[(size_t)(rowbase + r0) * UU + col0 + g0];
    const __bf16* kb1 = kb0 + 32 * (size_t)UU;
    const __bf16* vb0 = &Vt[(size_t)(col0 + r0) * BT + rowbase + g0];
    const __bf16* vb1 = vb0 + 32 * (size_t)BT;
    const float* kab = &kadd[rowbase + quad * 4];

#define STAGE_TILE(BUF, KP0, KP1, VP0, VP1)   \
    GLL16((KP0), &ks[BUF][c0 * 8]);           \
    GLL16((KP1), &ks[BUF][c0 * 8 + 2048]);    \
    GLL16((VP0), &vt[BUF][c0 * 8]);           \
    GLL16((VP1), &vt[BUF][c0 * 8 + 2048]);

#define LOADKA(KT)                            \
    _Pragma("unroll")                         \
    for (int ct = 0; ct < 4; ++ct)            \
        ka[ct] = *(const f32x4*)&kab[(KT) * 64 + ct * 16];

    float lpA = 0.f, lpB = 0.f;
    f32x4 ocA[4], ocB[4];
#pragma unroll
    for (int dt = 0; dt < 4; ++dt) {
        ocA[dt] = (f32x4){0.f, 0.f, 0.f, 0.f};
        ocB[dt] = (f32x4){0.f, 0.f, 0.f, 0.f};
    }
    int cur = 0;
    f32x4 ka[4];
    bf16x8 bqA0, bqA1, bqB0, bqB1;

// one 64q x 64k core: QK (swapped operands) + softmax + P via wave-private ps + PV
#define ATTN_CORE(KSC, VTC, DIAG, BQ0, BQ1, LP, OC)                            \
  {                                                                            \
    const __bf16* ksc = (KSC);                                                 \
    const __bf16* vtc = (VTC);                                                 \
    _Pragma("unroll")                                                          \
    for (int ct = 0; ct < 4; ++ct) {                                           \
      int krow = ct * 16 + nn;                                                 \
      bf16x8 a0 = *(const bf16x8*)&ksc[krow * 64 + ((quad ^ s7) * 8)];         \
      bf16x8 a1 = *(const bf16x8*)&ksc[krow * 64 + (((4 + quad) ^ s7) * 8)];   \
      f32x4 sc = (f32x4){0.f, 0.f, 0.f, 0.f};                                  \
      __builtin_amdgcn_s_setprio(1);                                           \
      sc = __builtin_amdgcn_mfma_f32_16x16x32_bf16(a0, (BQ0), sc, 0, 0, 0);    \
      sc = __builtin_amdgcn_mfma_f32_16x16x32_bf16(a1, (BQ1), sc, 0, 0, 0);    \
      __builtin_amdgcn_s_setprio(0);                                           \
      bf16x4 pw;                                                               \
      _Pragma("unroll")                                                        \
      for (int r = 0; r < 4; ++r) {                                            \
        float arg = fmaf(sc[r], C2EXP, ka[ct][r]);                             \
        if (DIAG) {                                                            \
          int kl = ct * 16 + quad * 4 + r;                                     \
          if (kl > prow) arg = -1.0e30f;                                       \
        }                                                                      \
        float pv = __builtin_amdgcn_exp2f(arg);                                \
        (LP) += pv;                                                            \
        pw[r] = (__bf16)pv;                                                    \
      }                                                                        \
      int chunk = ct * 2 + (quad >> 1);                                        \
      *(bf16x4*)&ps[prow * 64 + ((chunk ^ s7) * 8) + (quad & 1) * 4] = pw;     \
    }                                                                          \
    bf16x8 bp0 = *(const bf16x8*)&ps[prow * 64 + ((quad ^ s7) * 8)];           \
    bf16x8 bp1 = *(const bf16x8*)&ps[prow * 64 + (((4 + quad) ^ s7) * 8)];     \
    __builtin_amdgcn_s_setprio(1);                                             \
    _Pragma("unroll")                                                          \
    for (int dt = 0; dt < 4; ++dt) {                                           \
      int vrow = dt * 16 + nn;                                                 \
      bf16x8 a0 = *(const bf16x8*)&vtc[vrow * 64 + ((quad ^ s7) * 8)];         \
      bf16x8 a1 = *(const bf16x8*)&vtc[vrow * 64 + (((4 + quad) ^ s7) * 8)];   \
      (OC)[dt] = __builtin_amdgcn_mfma_f32_16x16x32_bf16(a0, bp0, (OC)[dt], 0, 0, 0); \
      (OC)[dt] = __builtin_amdgcn_mfma_f32_16x16x32_bf16(a1, bp1, (OC)[dt], 0, 0, 0); \
    }                                                                          \
    __builtin_amdgcn_s_setprio(0);                                             \
  }

    if (half == 0) {
        // ---------- fused jobs: A = q-tile qa keys 0..qa (diag at kt==qa),
        //                        B1 = q-tile qb keys 0..15-p (never diag) ----------
        const int nA = qa + 1, nB = 16 - p;
        const int nmax = nA > nB ? nA : nB;
        {
            const __bf16* qrp = &Q[(size_t)(rowbase + qa * 64 + prow) * UU + col0];
            bqA0 = *(const bf16x8*)&qrp[quad * 8];
            bqA1 = *(const bf16x8*)&qrp[32 + quad * 8];
            const __bf16* qrq = &Q[(size_t)(rowbase + qb * 64 + prow) * UU + col0];
            bqB0 = *(const bf16x8*)&qrq[quad * 8];
            bqB1 = *(const bf16x8*)&qrq[32 + quad * 8];
        }
        const __bf16* kp0 = kb0; const __bf16* kp1 = kb1;
        const __bf16* vp0 = vb0; const __bf16* vp1 = vb1;
        STAGE_TILE(0, kp0, kp1, vp0, vp1)
        kp0 += KSTRIDE; kp1 += KSTRIDE; vp0 += 64; vp1 += 64;
        asm volatile("s_waitcnt vmcnt(0)" ::: "memory");
        __builtin_amdgcn_s_barrier();

        for (int kt = 0; kt < nmax; ++kt) {
            LOADKA(kt)
            __builtin_amdgcn_sched_barrier(0);
            if (kt + 1 < nmax) {
                STAGE_TILE(cur ^ 1, kp0, kp1, vp0, vp1)
                kp0 += KSTRIDE; kp1 += KSTRIDE; vp0 += 64; vp1 += 64;
            }
            __builtin_amdgcn_sched_barrier(0);
            if (kt < nA) {
                ATTN_CORE(ks[cur], vt[cur], kt == qa, bqA0, bqA1, lpA, ocA)
            }
            if (kt < nB) {
                ATTN_CORE(ks[cur], vt[cur], false, bqB0, bqB1, lpB, ocB)
            }
            cur ^= 1;
            if (kt + 1 < nmax) {
                asm volatile("s_waitcnt vmcnt(0)" ::: "memory");
                __builtin_amdgcn_s_barrier();
            }
        }
        // epilogue A: COMPLETE output for q-tile qa -> final bf16 (qsel & /l applied)
        {
            float l = lpA;
            l += __shfl_xor(l, 16, 64);
            l += __shfl_xor(l, 32, 64);
            const int grow = rowbase + qa * 64 + prow;
            float qsel = (kadd[grow] < -1.0e29f) ? 0.f : 1.f;
            float mult = qsel / fmaxf(l, 1e-37f);
#pragma unroll
            for (int dt = 0; dt < 4; ++dt) {
                bf16x4 ov;
                ov[0] = (__bf16)(ocA[dt][0] * mult); ov[1] = (__bf16)(ocA[dt][1] * mult);
                ov[2] = (__bf16)(ocA[dt][2] * mult); ov[3] = (__bf16)(ocA[dt][3] * mult);
                *(bf16x4*)&Obf[(size_t)grow * UU + col0 + dt * 16 + quad * 4] = ov;
            }
        }
        // epilogue B1: f32 partial (compact upper-half rows) + l
        {
            float l = lpB;
            l += __shfl_xor(l, 16, 64);
            l += __shfl_xor(l, 32, 64);
            const int grow = rowbase + qb * 64 + prow;
            if (quad == 0) lq0[(size_t)grow * HH + h] = l;
            size_t orow = (size_t)(grow - (b + 1) * 1024);
#pragma unroll
            for (int dt = 0; dt < 4; ++dt)
                *(f32x4*)&Op0[orow * UU + col0 + dt * 16 + quad * 4] = ocB[dt];
        }
    } else {
        // ---------- job B part 2: q-tile qb, key tiles 16-p..31-p (diag last) ----------
        const int k0t = 16 - p;
        {
            const __bf16* qrow = &Q[(size_t)(rowbase + qb * 64 + prow) * UU + col0];
            bqA0 = *(const bf16x8*)&qrow[quad * 8];
            bqA1 = *(const bf16x8*)&qrow[32 + quad * 8];
        }
        const __bf16* kp0 = kb0 + (size_t)k0t * KSTRIDE;
        const __bf16* kp1 = kb1 + (size_t)k0t * KSTRIDE;
        const __bf16* vp0 = vb0 + k0t * 64;
        const __bf16* vp1 = vb1 + k0t * 64;
        STAGE_TILE(0, kp0, kp1, vp0, vp1)
        kp0 += KSTRIDE; kp1 += KSTRIDE; vp0 += 64; vp1 += 64;
        asm volatile("s_waitcnt vmcnt(0)" ::: "memory");
        __builtin_amdgcn_s_barrier();

        for (int i = 0; i < 15; ++i) {
            LOADKA(k0t + i)
            __builtin_amdgcn_sched_barrier(0);
            STAGE_TILE(cur ^ 1, kp0, kp1, vp0, vp1)
            kp0 += KSTRIDE; kp1 += KSTRIDE; vp0 += 64; vp1 += 64;
            __builtin_amdgcn_sched_barrier(0);
            ATTN_CORE(ks[cur], vt[cur], false, bqA0, bqA1, lpA, ocA)
            cur ^= 1;
            asm volatile("s_waitcnt vmcnt(0)" ::: "memory");
            __builtin_amdgcn_s_barrier();
        }
        LOADKA(k0t + 15)
        ATTN_CORE(ks[cur], vt[cur], true, bqA0, bqA1, lpA, ocA)  // kt = qb: diagonal
        // epilogue B2: f32 partial (compact upper-half rows) + l
        {
            float l = lpA;
            l += __shfl_xor(l, 16, 64);
            l += __shfl_xor(l, 32, 64);
            const int grow = rowbase + qb * 64 + prow;
            if (quad == 0) lq1[(size_t)grow * HH + h] = l;
            size_t orow = (size_t)(grow - (b + 1) * 1024);
#pragma unroll
            for (int dt = 0; dt < 4; ++dt)
                *(f32x4*)&Op1[orow * UU + col0 + dt * 16 + quad * 4] = ocA[dt];
        }
    }
#undef ATTN_CORE
#undef STAGE_TILE
#undef LOADKA
}

// ---------------- combine partials + residual + layernorm ----------------
__global__ __launch_bounds__(256) void ln_kernel(
    const __bf16* __restrict__ Obf, const float* __restrict__ Op0,
    const float* __restrict__ Op1, const float* __restrict__ lq0,
    const float* __restrict__ lq1, const float* __restrict__ kadd,
    const float* __restrict__ x, const float* __restrict__ gamma,
    const float* __restrict__ beta, float* __restrict__ out) {
    int row = blockIdx.x;
    int b = row >> 11;
    int qt = (row & (TT - 1)) >> 6;
    size_t base = (size_t)row * UU;
    int t = threadIdx.x;
    float v0, v1, v2, v3;
    float4 xv = *(const float4*)&x[base + t * 4];
    if (qt < 16) {
        // lower half: attention output is final bf16 (mask & /l already applied)
        bf16x4 ov = *(const bf16x4*)&Obf[base + t * 4];
        v0 = (float)ov[0] + xv.x; v1 = (float)ov[1] + xv.y;
        v2 = (float)ov[2] + xv.z; v3 = (float)ov[3] + xv.w;
    } else {
        // upper half: combine the two f32 partials
        int h = t >> 4;
        float l = lq0[(size_t)row * HH + h] + lq1[(size_t)row * HH + h];
        size_t base1 = (size_t)(row - (b + 1) * 1024) * UU;
        f32x4 o0 = *(const f32x4*)&Op0[base1 + t * 4];
        f32x4 o1 = *(const f32x4*)&Op1[base1 + t * 4];
        float qsel = (kadd[row] < -1.0e29f) ? 0.f : 1.f;
        float mult = qsel / fmaxf(l, 1e-37f);
        v0 = (o0[0] + o1[0]) * mult + xv.x; v1 = (o0[1] + o1[1]) * mult + xv.y;
        v2 = (o0[2] + o1[2]) * mult + xv.z; v3 = (o0[3] + o1[3]) * mult + xv.w;
    }
    float s1 = v0 + v1 + v2 + v3;
    float s2 = v0 * v0 + v1 * v1 + v2 * v2 + v3 * v3;
#pragma unroll
    for (int off = 32; off; off >>= 1) {
        s1 += __shfl_down(s1, off, 64);
        s2 += __shfl_down(s2, off, 64);
    }
    __shared__ float r1[4], r2[4];
    int lane = t & 63, w = t >> 6;
    if (lane == 0) { r1[w] = s1; r2[w] = s2; }
    __syncthreads();
    s1 = r1[0] + r1[1] + r1[2] + r1[3];
    s2 = r2[0] + r2[1] + r2[2] + r2[3];
    float mean = s1 * (1.0f / 1024.0f);
    float var = s2 * (1.0f / 1024.0f) - mean * mean;
    float rstd = rsqrtf(var + 1e-8f);
    float4 g = *(const float4*)&gamma[t * 4];
    float4 be = *(const float4*)&beta[t * 4];
    float4 ores;
    ores.x = g.x * (v0 - mean) * rstd + be.x;
    ores.y = g.y * (v1 - mean) * rstd + be.y;
    ores.z = g.z * (v2 - mean) * rstd + be.z;
    ores.w = g.w * (v3 - mean) * rstd + be.w;
    *(float4*)&out[base + t * 4] = ores;
}

extern "C" void kernel_launch(void* const* d_in, const int* in_sizes, int n_in,
                              void* d_out, int out_size, void* d_ws, size_t ws_size,
                              hipStream_t stream) {
    const float* x     = (const float*)d_in[0];
    const float* Wq    = (const float*)d_in[1];
    const float* bq    = (const float*)d_in[2];
    const float* Wk    = (const float*)d_in[3];
    const float* bk    = (const float*)d_in[4];
    const float* Wv    = (const float*)d_in[5];
    const float* bv    = (const float*)d_in[6];
    const float* gamma = (const float*)d_in[7];
    const float* beta  = (const float*)d_in[8];
    float* out = (float*)d_out;

    char* wsb = (char*)d_ws;
    const size_t MB = 1024ull * 1024;
    __bf16* xb  = (__bf16*)(wsb);                // 0..8 MiB   (dead after qkv)
    __bf16* Wt  = (__bf16*)(wsb + 8 * MB);       // 8..14 MiB  (dead after qkv)
    __bf16* Obf = (__bf16*)(wsb);                // 0..8 MiB   (aliases xb; lower-half rows)
    float* Op0  = (float*)(wsb + 8 * MB);        // 8..16 MiB  (aliases Wt; compact upper rows)
    __bf16* Qb  = (__bf16*)(wsb + 16 * MB);      // 8 MiB
    __bf16* Kb  = (__bf16*)(wsb + 24 * MB);      // 8 MiB
    __bf16* Vt  = (__bf16*)(wsb + 32 * MB);      // 8 MiB
    float* kadd = (float*)(wsb + 40 * MB);       // 16 KiB
    float* Op1  = (float*)(wsb + 41 * MB);       // 8 MiB (compact upper rows)
    float* lq0  = (float*)(wsb + 49 * MB);       // 256 KiB
    float* lq1  = (float*)(wsb + 50 * MB);       // 256 KiB

    prep_kernel<<<dim3(BT + 768), dim3(256), 0, stream>>>(x, kadd, xb, Wq, Wk, Wv, Wt);
    qkv_mfma<<<dim3(BT / 128, UU / 128, 3), dim3(256), 0, stream>>>(
        xb, Wt, bq, bk, bv, Qb, Kb, Vt);
    attn_mfma<<<dim3(BB * HH, 32), dim3(256), 0, stream>>>(
        Qb, Kb, Vt, kadd, Obf, Op0, Op1, lq0, lq1);
    ln_kernel<<<dim3(BT), dim3(256), 0, stream>>>(
        Obf, Op0, Op1, lq0, lq1, kadd, x, gamma, beta, out);
}